// Round 4
// baseline (2712.044 us; speedup 1.0000x reference)
//
#include <hip/hip_runtime.h>
#include <stdint.h>

// ---------------------------------------------------------------------------
// NIVR: coord-MLP over 512x512 grid.
//   pre_kernel (1025 blocks): coord posenc tables Tx, Ty (tvec NOT folded);
//                             W2f -> bf16 frag-swizzled W2s; time branch ->
//                             tvec[512] (b1f + phi@W1f). All independent =>
//                             single launch (was 2 serialized launches).
//   main: h1 = relu(Tx[x]+Ty[y]+tvec[k]); layer2 via MFMA bf16 16x16x32
//         (swapped operands => acc holds h2^T); fused layer3 epilogue.
//
// R13 vs R12: occupancy was LDS-bound: 71680B/block => 2 blocks/CU = 16
// waves/CU (50%), while matrix/DS/L2 floors are ~150-160k cyc/CU each and
// wall was 370k => all pipes ~40%, latency-bound. R13:
//  - A staged in two K-halves through ONE 32KB buffer (fill/bar/loop x2):
//    LDS 38912B => 4 blocks/CU = 32 waves/CU (100%). 2 extra block-local
//    barriers, covered by 4 independently-phased blocks/CU.
//  - __launch_bounds__(512,8); stagger kofs=w over 8 steps; setprio kept.
//  - tvec unfolded from Tx => pre fully parallel, one launch (saves ~10us
//    + serialization of the old pre0).
// Live regs ~140 combined (64 acc AGPR + 32 breg + 16 a + misc) <= 256 cap.
// ---------------------------------------------------------------------------

typedef short bf16x8 __attribute__((ext_vector_type(8)));
typedef float f32x4 __attribute__((ext_vector_type(4)));

#define PI_F 3.14159265358979323846f
#define SIDE 512
#define NPIX (SIDE * SIDE)

__device__ __forceinline__ unsigned short f2bf(float f) {
  unsigned int u = __float_as_uint(f);
  u += 0x7fffu + ((u >> 16) & 1u);
  return (unsigned short)(u >> 16);
}

// ---------------------------------------------------------------------------
// pre: 1025 blocks x 512 threads.
//   b in [0,512)    : Tx[b][k] = sum_l enc[l] W1f[l][k]        (rows 0..19)
//                     Ty[b][k] = sum_l enc[l] W1f[20+l][k]     (rows 20..39)
//   b in [512,1024) : W2f -> bf16 frag-swizzled W2s (k-row = b-512)
//                     W2s[ks*16384 + nt*512 + q*128 + ni*8 + j]
//                       = bf16(W2f[ks*32 + q*8 + j][nt*16 + ni])
//   b == 1024       : time branch -> tvec[k] = b1f[k] + phi @ W1f rows 40..167
// ---------------------------------------------------------------------------
__global__ void pre_kernel(const float* __restrict__ W1p, const float* __restrict__ b1p,
                           const float* __restrict__ W2p, const float* __restrict__ b2p,
                           const float* __restrict__ W1f, const float* __restrict__ b1f,
                           const float* __restrict__ W2f, const int* __restrict__ idx,
                           float* __restrict__ Tx, float* __restrict__ Ty,
                           unsigned short* __restrict__ W2s, float* __restrict__ tvec) {
  const int b = blockIdx.x;
  const int t = threadIdx.x;

  if (b == 1024) {
    // ---- time branch (old pre0) ----
    __shared__ float r_s[32];
    __shared__ float h_s[256];
    __shared__ float phi_s[128];
    if (t < 16) {
      float tt = (float)idx[0] / 300.0f;
      float ang = tt * ldexpf(PI_F, t);
      r_s[t] = sinf(ang);
      r_s[16 + t] = cosf(ang);
    }
    __syncthreads();
    if (t < 256) {
      float a = b1p[t];
#pragma unroll
      for (int i = 0; i < 32; ++i) a += r_s[i] * W1p[i * 256 + t];
      h_s[t] = fmaxf(a, 0.f);
    }
    __syncthreads();
    if (t < 128) {
      float a = b2p[t];
      for (int i = 0; i < 256; ++i) a += h_s[i] * W2p[i * 128 + t];
      phi_s[t] = a;
    }
    __syncthreads();
    {
      float tv = b1f[t];
      for (int p = 0; p < 128; ++p) tv += phi_s[p] * W1f[(40 + p) * 512 + t];
      tvec[t] = tv;
    }
    return;
  }

  if (b >= 512) {
    const int k = b - 512, n = t;
    const int ks = k >> 5, q = (k >> 3) & 3, j = k & 7;
    const int nt = n >> 4, ni = n & 15;
    W2s[ks * 16384 + nt * 512 + q * 128 + ni * 8 + j] = f2bf(W2f[k * 512 + n]);
    return;
  }

  __shared__ float enc[20];
  if (t < 10) {
    float u = (float)b / 512.0f;
    float ang = u * ldexpf(PI_F, t);
    enc[t] = sinf(ang);
    enc[10 + t] = cosf(ang);
  }
  __syncthreads();
  {
    float ax = 0.f, ay = 0.f;
#pragma unroll
    for (int l = 0; l < 20; ++l) {
      ax += enc[l] * W1f[l * 512 + t];
      ay += enc[l] * W1f[(20 + l) * 512 + t];
    }
    Tx[b * 512 + t] = ax;
    Ty[b * 512 + t] = ay;
  }
}

// ---------------------------------------------------------------------------
// Main fused kernel. Block = 512 thr (8 waves), BM=64 (8x8 patch), BN=512,
// K=512 in 2 halves of 8 steps (32 k each). Wave w owns N-slice [w*64,+64).
// A half-tile (32KB) staged in LDS per half; B via depth-1 register prefetch.
// Wave w walks each half starting at local step w (stagger; acc order-free).
// MFMA operands swapped: acc[mt][nt][r] = h2[pix=mt*16+lr][col=w*64+nt*16+q*4+r]
// ---------------------------------------------------------------------------
__global__ __launch_bounds__(512, 8) void main_kernel(
    const float* __restrict__ Tx, const float* __restrict__ Ty,
    const float* __restrict__ tvec,
    const unsigned short* __restrict__ W2s, const float* __restrict__ b2f,
    const float* __restrict__ W3f, const float* __restrict__ b3f,
    float* __restrict__ out) {
  __shared__ __attribute__((aligned(16))) unsigned short Ab[8 * 2048];  // 32KB
  __shared__ float part[8][64][3];                                      // 6KB

  const int t = threadIdx.x;
  const int w = t >> 6;            // wave id 0..7  (N-slice)
  const int lane = t & 63;
  const int q = lane >> 4;
  const int lr = lane & 15;
  const int x0 = blockIdx.x * 8, y0 = blockIdx.y * 8;

  // per-wave K-phase offset within each 8-step half (SGPR)
  const int kofs = __builtin_amdgcn_readfirstlane(w & 7);

  // B: wave w owns nt-slots w*4..w*4+3; frag (gks,nt) at +gks*16384 + nt*512;
  // lane reads at +lane*8 (16B, coalesced 1KB/wave).
  const unsigned short* bptr = W2s + (w * 4) * 512 + lane * 8;

  bf16x8 breg[2][4];
#pragma unroll
  for (int nt = 0; nt < 4; ++nt)
    breg[0][nt] = *(const bf16x8*)(bptr + kofs * 16384 + nt * 512);

  // A fill geometry: thread (p = t>>3, s = t&7) covers pixel p,
  // k = g*32 + s*4..+3; frag slot abase, conflict-free (R5-verified).
  const int p = t >> 3, s = t & 7;
  const int xi = x0 + (p >> 3), yi = y0 + (p & 7);
  const float* txp = Tx + xi * 512 + s * 4;
  const float* typ = Ty + yi * 512 + s * 4;
  const float* tvp = tvec + s * 4;
  const int abase = (((p >> 4) * 4 + (s >> 1)) * 16 + (p & 15)) * 8 + (s & 1) * 4;

  f32x4 acc[4][4];
#pragma unroll
  for (int i = 0; i < 4; ++i)
#pragma unroll
    for (int j2 = 0; j2 < 4; ++j2) acc[i][j2] = (f32x4){0.f, 0.f, 0.f, 0.f};

  // ---- fill one 8-step half of A into Ab ----
  auto fill_half = [&](int h) {
#pragma unroll
    for (int ks = 0; ks < 8; ++ks) {
      const int g = h * 8 + ks;
      float4 a = *(const float4*)(txp + g * 32);
      float4 b = *(const float4*)(typ + g * 32);
      float4 tv = *(const float4*)(tvp + g * 32);
      float v0 = fmaxf(a.x + b.x + tv.x, 0.f);
      float v1 = fmaxf(a.y + b.y + tv.y, 0.f);
      float v2 = fmaxf(a.z + b.z + tv.z, 0.f);
      float v3 = fmaxf(a.w + b.w + tv.w, 0.f);
      uint2 pk;
      asm("v_cvt_pk_bf16_f32 %0, %1, %2" : "=v"(pk.x) : "v"(v0), "v"(v1));
      asm("v_cvt_pk_bf16_f32 %0, %1, %2" : "=v"(pk.y) : "v"(v2), "v"(v3));
      *(uint2*)&Ab[ks * 2048 + abase] = pk;
    }
  };

  // ---- one 8-step K-half, wave-staggered, B prefetch depth 1 ----
  auto kloop_half = [&](int h) {
#pragma unroll
    for (int ks = 0; ks < 8; ++ks) {
      const int kkl = (ks + kofs) & 7;   // local step this wave computes now
      if (ks < 7) {
        const int knl = (kkl + 1) & 7;
#pragma unroll
        for (int nt = 0; nt < 4; ++nt)
          breg[(ks + 1) & 1][nt] =
              *(const bf16x8*)(bptr + (h * 8 + knl) * 16384 + nt * 512);
      } else if (h == 0) {
        // first B of half 1 (local step kofs) -> breg[0] (parity continues)
#pragma unroll
        for (int nt = 0; nt < 4; ++nt)
          breg[0][nt] = *(const bf16x8*)(bptr + (8 + kofs) * 16384 + nt * 512);
      }
      // A-frags for local step kkl: 4 ds_read_b128 sharing one vaddr
      const unsigned short* arow = &Ab[kkl * 2048 + lane * 8];
      bf16x8 a0 = *(const bf16x8*)&arow[0 * 512];
      bf16x8 a1 = *(const bf16x8*)&arow[1 * 512];
      bf16x8 a2 = *(const bf16x8*)&arow[2 * 512];
      bf16x8 a3 = *(const bf16x8*)&arow[3 * 512];
      __builtin_amdgcn_s_setprio(1);
#pragma unroll
      for (int nt = 0; nt < 4; ++nt) {
        acc[0][nt] = __builtin_amdgcn_mfma_f32_16x16x32_bf16(
            breg[ks & 1][nt], a0, acc[0][nt], 0, 0, 0);
        acc[1][nt] = __builtin_amdgcn_mfma_f32_16x16x32_bf16(
            breg[ks & 1][nt], a1, acc[1][nt], 0, 0, 0);
        acc[2][nt] = __builtin_amdgcn_mfma_f32_16x16x32_bf16(
            breg[ks & 1][nt], a2, acc[2][nt], 0, 0, 0);
        acc[3][nt] = __builtin_amdgcn_mfma_f32_16x16x32_bf16(
            breg[ks & 1][nt], a3, acc[3][nt], 0, 0, 0);
      }
      __builtin_amdgcn_s_setprio(0);
    }
  };

  fill_half(0);
  __syncthreads();   // publishes A half 0
  kloop_half(0);
  __syncthreads();   // all waves done reading half 0
  fill_half(1);
  __syncthreads();   // publishes A half 1
  kloop_half(1);

  // ---- epilogue: h2 = relu(acc + b2f); rgb partial = h2 @ W3f.
  // Layer-3 k-dim (col) lives on (q,r) in-register; streamed per-nt.
  // Reduce over q via shfl_xor 16,32. ----
  {
    float p3[4][3];
#pragma unroll
    for (int mt = 0; mt < 4; ++mt) {
      p3[mt][0] = 0.f; p3[mt][1] = 0.f; p3[mt][2] = 0.f;
    }
#pragma unroll
    for (int nt = 0; nt < 4; ++nt) {
      const int k0 = w * 64 + nt * 16 + q * 4;
      float4 bv = *(const float4*)&b2f[k0];
      float bb[4] = {bv.x, bv.y, bv.z, bv.w};
      float4 u0 = *(const float4*)&W3f[k0 * 3 + 0];
      float4 u1 = *(const float4*)&W3f[k0 * 3 + 4];
      float4 u2 = *(const float4*)&W3f[k0 * 3 + 8];
      float wv[4][3];
      wv[0][0] = u0.x; wv[0][1] = u0.y; wv[0][2] = u0.z;
      wv[1][0] = u0.w; wv[1][1] = u1.x; wv[1][2] = u1.y;
      wv[2][0] = u1.z; wv[2][1] = u1.w; wv[2][2] = u2.x;
      wv[3][0] = u2.y; wv[3][1] = u2.z; wv[3][2] = u2.w;
#pragma unroll
      for (int mt = 0; mt < 4; ++mt)
#pragma unroll
        for (int r = 0; r < 4; ++r) {
          float h2 = fmaxf(acc[mt][nt][r] + bb[r], 0.f);
          p3[mt][0] += h2 * wv[r][0];
          p3[mt][1] += h2 * wv[r][1];
          p3[mt][2] += h2 * wv[r][2];
        }
    }
#pragma unroll
    for (int d = 16; d < 64; d <<= 1)
#pragma unroll
      for (int mt = 0; mt < 4; ++mt)
#pragma unroll
        for (int cc = 0; cc < 3; ++cc)
          p3[mt][cc] += __shfl_xor(p3[mt][cc], d, 64);
    if (q < 3) {
#pragma unroll
      for (int mt = 0; mt < 4; ++mt) part[w][mt * 16 + lr][q] = p3[mt][q];
    }
  }
  __syncthreads();
  if (t < 192) {
    const int c = t >> 6, mm = t & 63;
    float sum = b3f[c];
#pragma unroll
    for (int ww = 0; ww < 8; ++ww) sum += part[ww][mm][c];
    const int n = (x0 + (mm >> 3)) * 512 + (y0 + (mm & 7));
    out[c * NPIX + n] = sum;
  }
}

// ---------------------------------------------------------------------------
// Inputs: 0 coords (unused), 1 W1p, 2 b1p, 3 W2p, 4 b2p, 5 W1f, 6 b1f,
//         7 W2f, 8 b2f, 9 W3f, 10 b3f, 11 idx
// ---------------------------------------------------------------------------
extern "C" void kernel_launch(void* const* d_in, const int* in_sizes, int n_in,
                              void* d_out, int out_size, void* d_ws, size_t ws_size,
                              hipStream_t stream) {
  const float* W1p = (const float*)d_in[1];
  const float* b1p = (const float*)d_in[2];
  const float* W2p = (const float*)d_in[3];
  const float* b2p = (const float*)d_in[4];
  const float* W1f = (const float*)d_in[5];
  const float* b1f = (const float*)d_in[6];
  const float* W2f = (const float*)d_in[7];
  const float* b2f = (const float*)d_in[8];
  const float* W3f = (const float*)d_in[9];
  const float* b3f = (const float*)d_in[10];
  const int* idx = (const int*)d_in[11];
  float* out = (float*)d_out;

  char* ws = (char*)d_ws;
  float* Tx = (float*)ws;                                    // 1 MB
  float* Ty = (float*)(ws + (1u << 20));                     // 1 MB
  unsigned short* W2s = (unsigned short*)(ws + (2u << 20));  // 512 KB
  float* tvec = (float*)(ws + (2u << 20) + (512u << 10));    // 2 KB

  hipLaunchKernelGGL(pre_kernel, dim3(1025), dim3(512), 0, stream,
                     W1p, b1p, W2p, b2p, W1f, b1f, W2f, idx, Tx, Ty, W2s, tvec);
  hipLaunchKernelGGL(main_kernel, dim3(64, 64), dim3(512), 0, stream,
                     Tx, Ty, tvec, W2s, b2f, W3f, b3f, out);
}

// Round 5
// 404.336 us; speedup vs baseline: 6.7074x; 6.7074x over previous
//
#include <hip/hip_runtime.h>
#include <stdint.h>

// ---------------------------------------------------------------------------
// NIVR: coord-MLP over 512x512 grid.
//   pre_kernel (1025 blocks): Tx, Ty posenc tables; W2f -> bf16 W2s
//   (32x32x16-frag-swizzled); time branch -> tvec[512].
//   main: h1 = relu(Tx[x]+Ty[y]+tvec[k]); layer2 via MFMA bf16 32x32x16
//   (swapped operands => acc holds h2^T); fused layer3 epilogue. Out [3][N].
//
// R14 vs R13: R13's launch_bounds(512,8) proved the reg pool is 2048/CU:
// 8 waves/SIMD => 64-reg cap < 64-reg acc => total spill (11.9GB scratch,
// 2.7ms). 16 waves/CU is the hard occupancy cap for a 64-reg-acc wave.
// So shrink the per-CU traffic floors instead (R12: L2-B 146k cyc = top):
//  - BM=128 (16x8 patch), 1024-thr block (16 waves, 4M x 4N): blocks/CU
//    16->8 => L2-B floor 146k->73k; wave M_wave=32 => per-wave A ds-reads
//    32KB => DS floor ~130k->~85k. acc stays 64 regs (32x128 per wave).
//  - MFMA 32x32x16: 1 A-frag + 4 B-frags + 4 MFMA per 16-k step; half the
//    issue slots, +13% matrix rate. Layouts: A/B op row=l&31,k=(l>>5)*8+j;
//    C/D col=lane&31 (pixel), row=(reg&3)+8*(reg>>2)+4*(lane>>5) (n).
//  - A in two 64KB K-halves (LDS 70KB total, same as R12; regs cap
//    residency at 1 block anyway). Stagger kofs=w (16 phases) + setprio.
//  - epilogue: n-dim on (reg,hi) => 1 shfl_xor(32); part[4nh][128][3].
// Live: 64 acc + 32 breg + 4 a + ~15 misc ~ 115 <= 128 (bounds(1024,4)).
// ---------------------------------------------------------------------------

typedef short bf16x8 __attribute__((ext_vector_type(8)));
typedef float f32x16 __attribute__((ext_vector_type(16)));

#define PI_F 3.14159265358979323846f
#define SIDE 512
#define NPIX (SIDE * SIDE)

__device__ __forceinline__ unsigned short f2bf(float f) {
  unsigned int u = __float_as_uint(f);
  u += 0x7fffu + ((u >> 16) & 1u);
  return (unsigned short)(u >> 16);
}

// ---------------------------------------------------------------------------
// pre: 1025 blocks x 512 threads.
//   b in [0,512)    : Tx[b][k] = sum_l enc[l] W1f[l][k]        (rows 0..19)
//                     Ty[b][k] = sum_l enc[l] W1f[20+l][k]     (rows 20..39)
//   b in [512,1024) : W2f -> bf16 W2s, 32x32x16 A-operand frags:
//                     frag (kstep=k>>4, nt32=n>>5), lane l=hi*32+lo holds
//                     W2f[kstep*16 + hi*8 + j][nt32*32 + lo] at
//                     W2s[kstep*8192 + nt32*512 + l*8 + j]
//   b == 1024       : time branch -> tvec[k] = b1f[k] + phi @ W1f rows 40..167
// ---------------------------------------------------------------------------
__global__ void pre_kernel(const float* __restrict__ W1p, const float* __restrict__ b1p,
                           const float* __restrict__ W2p, const float* __restrict__ b2p,
                           const float* __restrict__ W1f, const float* __restrict__ b1f,
                           const float* __restrict__ W2f, const int* __restrict__ idx,
                           float* __restrict__ Tx, float* __restrict__ Ty,
                           unsigned short* __restrict__ W2s, float* __restrict__ tvec) {
  const int b = blockIdx.x;
  const int t = threadIdx.x;

  if (b == 1024) {
    __shared__ float r_s[32];
    __shared__ float h_s[256];
    __shared__ float phi_s[128];
    if (t < 16) {
      float tt = (float)idx[0] / 300.0f;
      float ang = tt * ldexpf(PI_F, t);
      r_s[t] = sinf(ang);
      r_s[16 + t] = cosf(ang);
    }
    __syncthreads();
    if (t < 256) {
      float a = b1p[t];
#pragma unroll
      for (int i = 0; i < 32; ++i) a += r_s[i] * W1p[i * 256 + t];
      h_s[t] = fmaxf(a, 0.f);
    }
    __syncthreads();
    if (t < 128) {
      float a = b2p[t];
      for (int i = 0; i < 256; ++i) a += h_s[i] * W2p[i * 128 + t];
      phi_s[t] = a;
    }
    __syncthreads();
    {
      float tv = b1f[t];
      for (int p = 0; p < 128; ++p) tv += phi_s[p] * W1f[(40 + p) * 512 + t];
      tvec[t] = tv;
    }
    return;
  }

  if (b >= 512) {
    const int k = b - 512, n = t;
    const int kstep = k >> 4, hi = (k >> 3) & 1, j = k & 7;
    const int nt32 = n >> 5, lo = n & 31;
    W2s[kstep * 8192 + nt32 * 512 + (hi * 32 + lo) * 8 + j] = f2bf(W2f[k * 512 + n]);
    return;
  }

  __shared__ float enc[20];
  if (t < 10) {
    float u = (float)b / 512.0f;
    float ang = u * ldexpf(PI_F, t);
    enc[t] = sinf(ang);
    enc[10 + t] = cosf(ang);
  }
  __syncthreads();
  {
    float ax = 0.f, ay = 0.f;
#pragma unroll
    for (int l = 0; l < 20; ++l) {
      ax += enc[l] * W1f[l * 512 + t];
      ay += enc[l] * W1f[(20 + l) * 512 + t];
    }
    Tx[b * 512 + t] = ax;
    Ty[b * 512 + t] = ay;
  }
}

// ---------------------------------------------------------------------------
// Main fused kernel. Block = 1024 thr (16 waves, 4M x 4N), BM=128 (16x8
// pixel patch), BN=512, K=512 in 2 halves of 16 steps (16 k each).
// Wave w: mq=w>>2 owns pixels [mq*32,+32); nh=w&3 owns cols [nh*128,+128).
// A half-tile (64KB) staged in LDS per half; B via depth-1 reg prefetch.
// Per 16-k step per wave: 1 A ds_read_b128, 4 B 16B loads, 4 MFMA 32x32x16.
// acc[nn] reg r: h2[pix = mq*32 + (lane&31)]
//               [n = nh*128 + nn*32 + (r&3) + 8*(r>>2) + 4*(lane>>5)]
// ---------------------------------------------------------------------------
__global__ __launch_bounds__(1024, 4) void main_kernel(
    const float* __restrict__ Tx, const float* __restrict__ Ty,
    const float* __restrict__ tvec,
    const unsigned short* __restrict__ W2s, const float* __restrict__ b2f,
    const float* __restrict__ W3f, const float* __restrict__ b3f,
    float* __restrict__ out) {
  __shared__ __attribute__((aligned(16))) unsigned short Ab[16 * 2048];  // 64KB: 16 steps x (128 pix x 16 k)
  __shared__ float part[4][128][3];                                      // 6KB

  const int t = threadIdx.x;
  const int w = t >> 6;            // wave id 0..15
  const int lane = t & 63;
  const int lo = lane & 31;
  const int hi = lane >> 5;
  const int mq = w >> 2;           // M quarter
  const int nh = w & 3;            // N slice
  const int x0 = blockIdx.x * 16, y0 = blockIdx.y * 8;

  // per-wave K-phase offset within each 16-step half (SGPR)
  const int kofs = __builtin_amdgcn_readfirstlane(w);

  // B: frag (kstep, nn) at W2s + kstep*8192 + (nh*4+nn)*512 + lane*8
  const unsigned short* bptr = W2s + (nh * 4) * 512 + lane * 8;

  bf16x8 breg[2][4];
#pragma unroll
  for (int nn = 0; nn < 4; ++nn)
    breg[0][nn] = *(const bf16x8*)(bptr + kofs * 8192 + nn * 512);

  // A fill geometry: thread (p = t>>3, s = t&7) covers pixel p,
  // k = chunk*32 + s*4..+3. Element (p,k) lives at
  // (k>>4)*2048 + (p>>5)*512 + ((k>>3)&1)*256 + (p&31)*8 + (k&7)
  // => frag read for wave mq at step kkl is linear in lane (conflict-free).
  const int p = t >> 3, s = t & 7;
  const int xi = x0 + (p >> 3), yi = y0 + (p & 7);
  const float* txp = Tx + xi * 512 + s * 4;
  const float* typ = Ty + yi * 512 + s * 4;
  const float* tvp = tvec + s * 4;
  const int abase = (p >> 5) * 512 + ((s >> 1) & 1) * 256 + (p & 31) * 8 + (s & 1) * 4;
  const int astep = s >> 2;  // which 16-k step within the 32-k chunk

  f32x16 acc[4];
#pragma unroll
  for (int nn = 0; nn < 4; ++nn)
#pragma unroll
    for (int r = 0; r < 16; ++r) acc[nn][r] = 0.f;

  // ---- fill one 16-step half of A into Ab (8 chunks of 32 k) ----
  auto fill_half = [&](int h) {
#pragma unroll
    for (int g = 0; g < 8; ++g) {
      const int gg = h * 8 + g;
      float4 a = *(const float4*)(txp + gg * 32);
      float4 b = *(const float4*)(typ + gg * 32);
      float4 tv = *(const float4*)(tvp + gg * 32);
      float v0 = fmaxf(a.x + b.x + tv.x, 0.f);
      float v1 = fmaxf(a.y + b.y + tv.y, 0.f);
      float v2 = fmaxf(a.z + b.z + tv.z, 0.f);
      float v3 = fmaxf(a.w + b.w + tv.w, 0.f);
      uint2 pk;
      asm("v_cvt_pk_bf16_f32 %0, %1, %2" : "=v"(pk.x) : "v"(v0), "v"(v1));
      asm("v_cvt_pk_bf16_f32 %0, %1, %2" : "=v"(pk.y) : "v"(v2), "v"(v3));
      *(uint2*)&Ab[(g * 2 + astep) * 2048 + abase] = pk;
    }
  };

  // ---- one 16-step K-half, wave-staggered, B prefetch depth 1 ----
  auto kloop_half = [&](int h) {
#pragma unroll
    for (int ks = 0; ks < 16; ++ks) {
      const int kkl = (ks + kofs) & 15;   // local step this wave computes now
      if (ks < 15) {
        const int knl = (kkl + 1) & 15;
#pragma unroll
        for (int nn = 0; nn < 4; ++nn)
          breg[(ks + 1) & 1][nn] =
              *(const bf16x8*)(bptr + (h * 16 + knl) * 8192 + nn * 512);
      } else if (h == 0) {
        // first B of half 1 (local step kofs) -> breg[0] (parity continues)
#pragma unroll
        for (int nn = 0; nn < 4; ++nn)
          breg[0][nn] = *(const bf16x8*)(bptr + (16 + kofs) * 8192 + nn * 512);
      }
      // A-frag for this wave's M-slice at local step kkl (1 ds_read_b128)
      bf16x8 af = *(const bf16x8*)&Ab[kkl * 2048 + mq * 512 + lane * 8];
      __builtin_amdgcn_s_setprio(1);
#pragma unroll
      for (int nn = 0; nn < 4; ++nn)
        acc[nn] = __builtin_amdgcn_mfma_f32_32x32x16_bf16(
            breg[ks & 1][nn], af, acc[nn], 0, 0, 0);
      __builtin_amdgcn_s_setprio(0);
    }
  };

  fill_half(0);
  __syncthreads();   // publishes A half 0
  kloop_half(0);
  __syncthreads();   // all waves done reading half 0
  fill_half(1);
  __syncthreads();   // publishes A half 1
  kloop_half(1);

  // ---- epilogue: h2 = relu(acc + b2f); rgb partial = h2 @ W3f.
  // Lane covers pixel mq*32+lo, n-cols nh*128 + nn*32 + rq*8 + hi*4 + e.
  // Single shfl_xor(32) combines the two hi-halves. ----
  {
    float p3[3] = {0.f, 0.f, 0.f};
    const int nb = nh * 128 + hi * 4;
#pragma unroll
    for (int nn = 0; nn < 4; ++nn) {
#pragma unroll
      for (int rq = 0; rq < 4; ++rq) {
        const int n0 = nb + nn * 32 + rq * 8;
        float4 bv = *(const float4*)&b2f[n0];
        float4 u0 = *(const float4*)&W3f[n0 * 3 + 0];
        float4 u1 = *(const float4*)&W3f[n0 * 3 + 4];
        float4 u2 = *(const float4*)&W3f[n0 * 3 + 8];
        float h0 = fmaxf(acc[nn][rq * 4 + 0] + bv.x, 0.f);
        float h1 = fmaxf(acc[nn][rq * 4 + 1] + bv.y, 0.f);
        float h2 = fmaxf(acc[nn][rq * 4 + 2] + bv.z, 0.f);
        float h3 = fmaxf(acc[nn][rq * 4 + 3] + bv.w, 0.f);
        p3[0] += h0 * u0.x + h1 * u0.w + h2 * u1.z + h3 * u2.y;
        p3[1] += h0 * u0.y + h1 * u1.x + h2 * u1.w + h3 * u2.z;
        p3[2] += h0 * u0.z + h1 * u1.y + h2 * u2.x + h3 * u2.w;
      }
    }
#pragma unroll
    for (int cc = 0; cc < 3; ++cc) p3[cc] += __shfl_xor(p3[cc], 32, 64);
    if (hi == 0) {
#pragma unroll
      for (int cc = 0; cc < 3; ++cc) part[nh][mq * 32 + lo][cc] = p3[cc];
    }
  }
  __syncthreads();
  if (t < 384) {
    const int c = t >> 7, pp = t & 127;
    float sum = b3f[c] + part[0][pp][c] + part[1][pp][c] +
                part[2][pp][c] + part[3][pp][c];
    out[c * NPIX + (x0 + (pp >> 3)) * 512 + (y0 + (pp & 7))] = sum;
  }
}

// ---------------------------------------------------------------------------
// Inputs: 0 coords (unused), 1 W1p, 2 b1p, 3 W2p, 4 b2p, 5 W1f, 6 b1f,
//         7 W2f, 8 b2f, 9 W3f, 10 b3f, 11 idx
// ---------------------------------------------------------------------------
extern "C" void kernel_launch(void* const* d_in, const int* in_sizes, int n_in,
                              void* d_out, int out_size, void* d_ws, size_t ws_size,
                              hipStream_t stream) {
  const float* W1p = (const float*)d_in[1];
  const float* b1p = (const float*)d_in[2];
  const float* W2p = (const float*)d_in[3];
  const float* b2p = (const float*)d_in[4];
  const float* W1f = (const float*)d_in[5];
  const float* b1f = (const float*)d_in[6];
  const float* W2f = (const float*)d_in[7];
  const float* b2f = (const float*)d_in[8];
  const float* W3f = (const float*)d_in[9];
  const float* b3f = (const float*)d_in[10];
  const int* idx = (const int*)d_in[11];
  float* out = (float*)d_out;

  char* ws = (char*)d_ws;
  float* Tx = (float*)ws;                                    // 1 MB
  float* Ty = (float*)(ws + (1u << 20));                     // 1 MB
  unsigned short* W2s = (unsigned short*)(ws + (2u << 20));  // 512 KB
  float* tvec = (float*)(ws + (2u << 20) + (512u << 10));    // 2 KB

  hipLaunchKernelGGL(pre_kernel, dim3(1025), dim3(512), 0, stream,
                     W1p, b1p, W2p, b2p, W1f, b1f, W2f, idx, Tx, Ty, W2s, tvec);
  hipLaunchKernelGGL(main_kernel, dim3(32, 64), dim3(1024), 0, stream,
                     Tx, Ty, tvec, W2s, b2f, W3f, b3f, out);
}

// Round 6
// 243.203 us; speedup vs baseline: 11.1514x; 1.6625x over previous
//
#include <hip/hip_runtime.h>
#include <stdint.h>

// ---------------------------------------------------------------------------
// NIVR: coord-MLP over 512x512 grid.
//   pre_kernel (1025 blocks): Tx, Ty posenc tables; W2f -> bf16 W2s
//   (32x32x16-frag-swizzled); time branch -> tvec[512].
//   main: h1 = relu(Tx[x]+Ty[y]+tvec[k]); layer2 via MFMA bf16 32x32x16
//   (swapped operands => acc holds h2^T); fused layer3 epilogue. Out [3][N].
//
// R15 vs R14: reg pool calibrated = 512 combined VGPR+AGPR per SIMD-lane:
//   R13 (512,8): cap 64  -> total spill (11.9GB).
//   R14 (1024,4): cap 128 < ~180 live -> moderate spill (545MB, 346us).
//   => 1024-thr blocks with 128-reg acc are infeasible; and R14's 2Mx4N
//      wave grid duplicated B reads 2x anyway.
// R15: BM=128 (16x8 patch) with 512-thr blocks, wave grid 1M x 8N:
//   each wave = ALL 128 pixels x own 64 n-cols. acc = 4 Mfrag x 2 Nfrag
//   x f32x16 = 128 regs; B per block = 512KB (no duplication).
//   launch_bounds(512,2) -> cap 256 >= ~190 live. 2 waves/SIMD, 1 blk/CU.
// Per-CU floors: matrix 55us (max), A-DS 41, B-L2 30 (was 61 at BM=64),
// fill ~12. Per-step per-CU: matrix 516 cyc > DS 384 > L2 286 => matrix-
// critical. Stagger kofs=w + setprio kept. A in two 64KB halves (LDS 76KB).
// ---------------------------------------------------------------------------

typedef short bf16x8 __attribute__((ext_vector_type(8)));
typedef float f32x16 __attribute__((ext_vector_type(16)));

#define PI_F 3.14159265358979323846f
#define SIDE 512
#define NPIX (SIDE * SIDE)

__device__ __forceinline__ unsigned short f2bf(float f) {
  unsigned int u = __float_as_uint(f);
  u += 0x7fffu + ((u >> 16) & 1u);
  return (unsigned short)(u >> 16);
}

// ---------------------------------------------------------------------------
// pre: 1025 blocks x 512 threads.
//   b in [0,512)    : Tx[b][k] = sum_l enc[l] W1f[l][k]        (rows 0..19)
//                     Ty[b][k] = sum_l enc[l] W1f[20+l][k]     (rows 20..39)
//   b in [512,1024) : W2f -> bf16 W2s, 32x32x16 A-operand frags:
//                     frag (kstep=k>>4, nt32=n>>5), lane l=hi*32+lo holds
//                     W2f[kstep*16 + hi*8 + j][nt32*32 + lo] at
//                     W2s[kstep*8192 + nt32*512 + l*8 + j]   (R14-verified)
//   b == 1024       : time branch -> tvec[k] = b1f[k] + phi @ W1f rows 40..167
// ---------------------------------------------------------------------------
__global__ void pre_kernel(const float* __restrict__ W1p, const float* __restrict__ b1p,
                           const float* __restrict__ W2p, const float* __restrict__ b2p,
                           const float* __restrict__ W1f, const float* __restrict__ b1f,
                           const float* __restrict__ W2f, const int* __restrict__ idx,
                           float* __restrict__ Tx, float* __restrict__ Ty,
                           unsigned short* __restrict__ W2s, float* __restrict__ tvec) {
  const int b = blockIdx.x;
  const int t = threadIdx.x;

  if (b == 1024) {
    __shared__ float r_s[32];
    __shared__ float h_s[256];
    __shared__ float phi_s[128];
    if (t < 16) {
      float tt = (float)idx[0] / 300.0f;
      float ang = tt * ldexpf(PI_F, t);
      r_s[t] = sinf(ang);
      r_s[16 + t] = cosf(ang);
    }
    __syncthreads();
    if (t < 256) {
      float a = b1p[t];
#pragma unroll
      for (int i = 0; i < 32; ++i) a += r_s[i] * W1p[i * 256 + t];
      h_s[t] = fmaxf(a, 0.f);
    }
    __syncthreads();
    if (t < 128) {
      float a = b2p[t];
      for (int i = 0; i < 256; ++i) a += h_s[i] * W2p[i * 128 + t];
      phi_s[t] = a;
    }
    __syncthreads();
    {
      float tv = b1f[t];
      for (int p = 0; p < 128; ++p) tv += phi_s[p] * W1f[(40 + p) * 512 + t];
      tvec[t] = tv;
    }
    return;
  }

  if (b >= 512) {
    const int k = b - 512, n = t;
    const int kstep = k >> 4, hi = (k >> 3) & 1, j = k & 7;
    const int nt32 = n >> 5, lo = n & 31;
    W2s[kstep * 8192 + nt32 * 512 + (hi * 32 + lo) * 8 + j] = f2bf(W2f[k * 512 + n]);
    return;
  }

  __shared__ float enc[20];
  if (t < 10) {
    float u = (float)b / 512.0f;
    float ang = u * ldexpf(PI_F, t);
    enc[t] = sinf(ang);
    enc[10 + t] = cosf(ang);
  }
  __syncthreads();
  {
    float ax = 0.f, ay = 0.f;
#pragma unroll
    for (int l = 0; l < 20; ++l) {
      ax += enc[l] * W1f[l * 512 + t];
      ay += enc[l] * W1f[(20 + l) * 512 + t];
    }
    Tx[b * 512 + t] = ax;
    Ty[b * 512 + t] = ay;
  }
}

// ---------------------------------------------------------------------------
// Main fused kernel. Block = 512 thr (8 waves), BM=128 (16x8 pixel patch),
// BN=512, K=512 in 2 halves of 16 steps (16 k each).
// Wave w: ALL 128 pixels x n-cols [w*64, +64) (no B duplication).
// Per 16-k step per wave: 4 A ds_read_b128 (one vaddr + imm offsets),
// 2 B 16B loads (depth-1 prefetch), 8 MFMA 32x32x16.
// acc[mf][nn] reg r: h2[pix = mf*32 + (lane&31)]
//                   [n = w*64 + nn*32 + (r&3) + 8*(r>>2) + 4*(lane>>5)]
// ---------------------------------------------------------------------------
__global__ __launch_bounds__(512, 2) void main_kernel(
    const float* __restrict__ Tx, const float* __restrict__ Ty,
    const float* __restrict__ tvec,
    const unsigned short* __restrict__ W2s, const float* __restrict__ b2f,
    const float* __restrict__ W3f, const float* __restrict__ b3f,
    float* __restrict__ out) {
  __shared__ __attribute__((aligned(16))) unsigned short Ab[16 * 2048];  // 64KB: 16 steps x (128 pix x 16 k)
  __shared__ float part[8][128][3];                                      // 12KB

  const int t = threadIdx.x;
  const int w = t >> 6;            // wave id 0..7 (owns n-slice [w*64,+64))
  const int lane = t & 63;
  const int lo = lane & 31;
  const int hi = lane >> 5;
  const int x0 = blockIdx.x * 16, y0 = blockIdx.y * 8;

  // per-wave K-phase offset within each 16-step half (SGPR)
  const int kofs = __builtin_amdgcn_readfirstlane(w);

  // B: frag (kstep, nn) at W2s + kstep*8192 + (w*2+nn)*512 + lane*8
  const unsigned short* bptr = W2s + (w * 2) * 512 + lane * 8;

  bf16x8 breg[2][2];
#pragma unroll
  for (int nn = 0; nn < 2; ++nn)
    breg[0][nn] = *(const bf16x8*)(bptr + kofs * 8192 + nn * 512);

  // A fill geometry: thread (p = t>>2, s = t&3) covers pixel p (0..127),
  // k = 16*step + s*4..+3. Element (p,k) at (shorts)
  //   (k>>4)*2048 + (p>>5)*512 + ((k>>3)&1)*256 + (p&31)*8 + (k&7)
  // Frag read at lane l: step*2048 + mf*512 + l*8  (1KB contiguous, c-free).
  const int p = t >> 2, s = t & 3;
  const int xi = x0 + (p >> 3), yi = y0 + (p & 7);
  const float* txp = Tx + xi * 512 + s * 4;
  const float* typ = Ty + yi * 512 + s * 4;
  const float* tvp = tvec + s * 4;
  const int abase = (p >> 5) * 512 + (s >> 1) * 256 + (p & 31) * 8 + (s & 1) * 4;

  f32x16 acc[4][2];
#pragma unroll
  for (int mf = 0; mf < 4; ++mf)
#pragma unroll
    for (int nn = 0; nn < 2; ++nn)
#pragma unroll
      for (int r = 0; r < 16; ++r) acc[mf][nn][r] = 0.f;

  // ---- fill one 16-step half of A into Ab ----
  auto fill_half = [&](int h) {
#pragma unroll
    for (int g = 0; g < 16; ++g) {
      const int kb = h * 256 + g * 16;   // + s*4 folded into pointers
      float4 a = *(const float4*)(txp + kb);
      float4 b = *(const float4*)(typ + kb);
      float4 tv = *(const float4*)(tvp + kb);
      float v0 = fmaxf(a.x + b.x + tv.x, 0.f);
      float v1 = fmaxf(a.y + b.y + tv.y, 0.f);
      float v2 = fmaxf(a.z + b.z + tv.z, 0.f);
      float v3 = fmaxf(a.w + b.w + tv.w, 0.f);
      uint2 pk;
      asm("v_cvt_pk_bf16_f32 %0, %1, %2" : "=v"(pk.x) : "v"(v0), "v"(v1));
      asm("v_cvt_pk_bf16_f32 %0, %1, %2" : "=v"(pk.y) : "v"(v2), "v"(v3));
      *(uint2*)&Ab[g * 2048 + abase] = pk;
    }
  };

  // ---- one 16-step K-half, wave-staggered, B prefetch depth 1 ----
  auto kloop_half = [&](int h) {
#pragma unroll
    for (int ks = 0; ks < 16; ++ks) {
      const int kkl = (ks + kofs) & 15;   // local step this wave computes now
      if (ks < 15) {
        const int knl = (kkl + 1) & 15;
#pragma unroll
        for (int nn = 0; nn < 2; ++nn)
          breg[(ks + 1) & 1][nn] =
              *(const bf16x8*)(bptr + (h * 16 + knl) * 8192 + nn * 512);
      } else if (h == 0) {
        // first B of half 1 (local step kofs) -> breg[0] (parity continues)
#pragma unroll
        for (int nn = 0; nn < 2; ++nn)
          breg[0][nn] = *(const bf16x8*)(bptr + (16 + kofs) * 8192 + nn * 512);
      }
      // A-frags for local step kkl: 4 ds_read_b128, one vaddr + imm offsets
      const unsigned short* arow = &Ab[kkl * 2048 + lane * 8];
      bf16x8 a0 = *(const bf16x8*)&arow[0 * 512];
      bf16x8 a1 = *(const bf16x8*)&arow[1 * 512];
      bf16x8 a2 = *(const bf16x8*)&arow[2 * 512];
      bf16x8 a3 = *(const bf16x8*)&arow[3 * 512];
      __builtin_amdgcn_s_setprio(1);
#pragma unroll
      for (int nn = 0; nn < 2; ++nn) {
        acc[0][nn] = __builtin_amdgcn_mfma_f32_32x32x16_bf16(
            breg[ks & 1][nn], a0, acc[0][nn], 0, 0, 0);
        acc[1][nn] = __builtin_amdgcn_mfma_f32_32x32x16_bf16(
            breg[ks & 1][nn], a1, acc[1][nn], 0, 0, 0);
        acc[2][nn] = __builtin_amdgcn_mfma_f32_32x32x16_bf16(
            breg[ks & 1][nn], a2, acc[2][nn], 0, 0, 0);
        acc[3][nn] = __builtin_amdgcn_mfma_f32_32x32x16_bf16(
            breg[ks & 1][nn], a3, acc[3][nn], 0, 0, 0);
      }
      __builtin_amdgcn_s_setprio(0);
    }
  };

  fill_half(0);
  __syncthreads();   // publishes A half 0
  kloop_half(0);
  __syncthreads();   // all waves done reading half 0
  fill_half(1);
  __syncthreads();   // publishes A half 1
  kloop_half(1);

  // ---- epilogue: h2 = relu(acc + b2f); rgb partial = h2 @ W3f.
  // Lane: pixels mf*32+lo, n-cols w*64 + nn*32 + rq*8 + hi*4 + e.
  // W3/bias loads hoisted over mf. shfl_xor(32) combines hi-halves. ----
  {
    float p3[4][3];
#pragma unroll
    for (int mf = 0; mf < 4; ++mf) {
      p3[mf][0] = 0.f; p3[mf][1] = 0.f; p3[mf][2] = 0.f;
    }
#pragma unroll
    for (int nn = 0; nn < 2; ++nn) {
#pragma unroll
      for (int rq = 0; rq < 4; ++rq) {
        const int n0 = w * 64 + nn * 32 + rq * 8 + hi * 4;
        float4 bv = *(const float4*)&b2f[n0];
        float4 u0 = *(const float4*)&W3f[n0 * 3 + 0];
        float4 u1 = *(const float4*)&W3f[n0 * 3 + 4];
        float4 u2 = *(const float4*)&W3f[n0 * 3 + 8];
#pragma unroll
        for (int mf = 0; mf < 4; ++mf) {
          float h0 = fmaxf(acc[mf][nn][rq * 4 + 0] + bv.x, 0.f);
          float h1 = fmaxf(acc[mf][nn][rq * 4 + 1] + bv.y, 0.f);
          float h2 = fmaxf(acc[mf][nn][rq * 4 + 2] + bv.z, 0.f);
          float h3 = fmaxf(acc[mf][nn][rq * 4 + 3] + bv.w, 0.f);
          p3[mf][0] += h0 * u0.x + h1 * u0.w + h2 * u1.z + h3 * u2.y;
          p3[mf][1] += h0 * u0.y + h1 * u1.x + h2 * u1.w + h3 * u2.z;
          p3[mf][2] += h0 * u0.z + h1 * u1.y + h2 * u2.x + h3 * u2.w;
        }
      }
    }
#pragma unroll
    for (int mf = 0; mf < 4; ++mf)
#pragma unroll
      for (int cc = 0; cc < 3; ++cc)
        p3[mf][cc] += __shfl_xor(p3[mf][cc], 32, 64);
    if (hi == 0) {
#pragma unroll
      for (int mf = 0; mf < 4; ++mf)
#pragma unroll
        for (int cc = 0; cc < 3; ++cc)
          part[w][mf * 32 + lo][cc] = p3[mf][cc];
    }
  }
  __syncthreads();
  if (t < 384) {
    const int c = t >> 7, pp = t & 127;
    float sum = b3f[c];
#pragma unroll
    for (int ww = 0; ww < 8; ++ww) sum += part[ww][pp][c];
    out[c * NPIX + (x0 + (pp >> 3)) * 512 + (y0 + (pp & 7))] = sum;
  }
}

// ---------------------------------------------------------------------------
// Inputs: 0 coords (unused), 1 W1p, 2 b1p, 3 W2p, 4 b2p, 5 W1f, 6 b1f,
//         7 W2f, 8 b2f, 9 W3f, 10 b3f, 11 idx
// ---------------------------------------------------------------------------
extern "C" void kernel_launch(void* const* d_in, const int* in_sizes, int n_in,
                              void* d_out, int out_size, void* d_ws, size_t ws_size,
                              hipStream_t stream) {
  const float* W1p = (const float*)d_in[1];
  const float* b1p = (const float*)d_in[2];
  const float* W2p = (const float*)d_in[3];
  const float* b2p = (const float*)d_in[4];
  const float* W1f = (const float*)d_in[5];
  const float* b1f = (const float*)d_in[6];
  const float* W2f = (const float*)d_in[7];
  const float* b2f = (const float*)d_in[8];
  const float* W3f = (const float*)d_in[9];
  const float* b3f = (const float*)d_in[10];
  const int* idx = (const int*)d_in[11];
  float* out = (float*)d_out;

  char* ws = (char*)d_ws;
  float* Tx = (float*)ws;                                    // 1 MB
  float* Ty = (float*)(ws + (1u << 20));                     // 1 MB
  unsigned short* W2s = (unsigned short*)(ws + (2u << 20));  // 512 KB
  float* tvec = (float*)(ws + (2u << 20) + (512u << 10));    // 2 KB

  hipLaunchKernelGGL(pre_kernel, dim3(1025), dim3(512), 0, stream,
                     W1p, b1p, W2p, b2p, W1f, b1f, W2f, idx, Tx, Ty, W2s, tvec);
  hipLaunchKernelGGL(main_kernel, dim3(32, 64), dim3(512), 0, stream,
                     Tx, Ty, tvec, W2s, b2f, W3f, b3f, out);
}

// Round 7
// 241.170 us; speedup vs baseline: 11.2454x; 1.0084x over previous
//
#include <hip/hip_runtime.h>
#include <stdint.h>

// ---------------------------------------------------------------------------
// NIVR: coord-MLP over 512x512 grid.
//   pre_kernel (1025 blocks): Tx, Ty posenc tables; W2f -> bf16 W2s
//   (32x32x16-frag-swizzled); time branch -> tvec[512].
//   main: h1 = relu(Tx[x]+Ty[y]+tvec[k]); layer2 via MFMA bf16 32x32x16
//   (swapped operands => acc holds h2^T); fused layer3 epilogue. Out [3][N].
//
// R16 vs R15: R15 regressed (184 vs R12's 154) despite the best floor-sum
// (matrix 55 + A-DS 39 + B-L2 30 = 129us): kloop wall ~1330 cyc/step vs 512
// ideal = ~800 cyc/step exposed latency. Cause: at 2 waves/SIMD the at-use
// A ds_reads (R11 dropped the prefetch, relying on 4-waves/SIMD TLP) have
// no sibling waves to hide behind -> intra-SIMD convoy. R16 restores
// ILP-based hiding, reg-budgeted for the 256-reg cap:
//  - areg[2][4] depth-1 rotation: A reads for ks+1 issued before ks's MFMAs
//    (loads ride 512 cyc of MFMA; lgkmcnt(4) not 0). breg depth-1 kept.
//  - whole A tile (32 steps, 128KB) filled ONCE: 1 barrier (was 3), no
//    half-boundary at-use loads; fill pipelines deep (acc/areg not live).
//  - LDS 140KB (1 block/CU -- regs force that anyway). Stagger kofs=4w/32.
// Live: 128 acc + 32 areg + 32 breg + ~25 misc ~ 217 <= 256 (512,2).
// ---------------------------------------------------------------------------

typedef short bf16x8 __attribute__((ext_vector_type(8)));
typedef float f32x16 __attribute__((ext_vector_type(16)));

#define PI_F 3.14159265358979323846f
#define SIDE 512
#define NPIX (SIDE * SIDE)

__device__ __forceinline__ unsigned short f2bf(float f) {
  unsigned int u = __float_as_uint(f);
  u += 0x7fffu + ((u >> 16) & 1u);
  return (unsigned short)(u >> 16);
}

// ---------------------------------------------------------------------------
// pre: 1025 blocks x 512 threads (unchanged from R15; R14/R15-verified).
//   b in [0,512)    : Tx[b][k] = sum_l enc[l] W1f[l][k]        (rows 0..19)
//                     Ty[b][k] = sum_l enc[l] W1f[20+l][k]     (rows 20..39)
//   b in [512,1024) : W2f -> bf16 W2s, 32x32x16 A-operand frags:
//                     W2s[kstep*8192 + nt32*512 + (hi*32+lo)*8 + j]
//                       = bf16(W2f[kstep*16 + hi*8 + j][nt32*32 + lo])
//   b == 1024       : time branch -> tvec[k] = b1f[k] + phi @ W1f rows 40..167
// ---------------------------------------------------------------------------
__global__ void pre_kernel(const float* __restrict__ W1p, const float* __restrict__ b1p,
                           const float* __restrict__ W2p, const float* __restrict__ b2p,
                           const float* __restrict__ W1f, const float* __restrict__ b1f,
                           const float* __restrict__ W2f, const int* __restrict__ idx,
                           float* __restrict__ Tx, float* __restrict__ Ty,
                           unsigned short* __restrict__ W2s, float* __restrict__ tvec) {
  const int b = blockIdx.x;
  const int t = threadIdx.x;

  if (b == 1024) {
    __shared__ float r_s[32];
    __shared__ float h_s[256];
    __shared__ float phi_s[128];
    if (t < 16) {
      float tt = (float)idx[0] / 300.0f;
      float ang = tt * ldexpf(PI_F, t);
      r_s[t] = sinf(ang);
      r_s[16 + t] = cosf(ang);
    }
    __syncthreads();
    if (t < 256) {
      float a = b1p[t];
#pragma unroll
      for (int i = 0; i < 32; ++i) a += r_s[i] * W1p[i * 256 + t];
      h_s[t] = fmaxf(a, 0.f);
    }
    __syncthreads();
    if (t < 128) {
      float a = b2p[t];
      for (int i = 0; i < 256; ++i) a += h_s[i] * W2p[i * 128 + t];
      phi_s[t] = a;
    }
    __syncthreads();
    {
      float tv = b1f[t];
      for (int p = 0; p < 128; ++p) tv += phi_s[p] * W1f[(40 + p) * 512 + t];
      tvec[t] = tv;
    }
    return;
  }

  if (b >= 512) {
    const int k = b - 512, n = t;
    const int kstep = k >> 4, hi = (k >> 3) & 1, j = k & 7;
    const int nt32 = n >> 5, lo = n & 31;
    W2s[kstep * 8192 + nt32 * 512 + (hi * 32 + lo) * 8 + j] = f2bf(W2f[k * 512 + n]);
    return;
  }

  __shared__ float enc[20];
  if (t < 10) {
    float u = (float)b / 512.0f;
    float ang = u * ldexpf(PI_F, t);
    enc[t] = sinf(ang);
    enc[10 + t] = cosf(ang);
  }
  __syncthreads();
  {
    float ax = 0.f, ay = 0.f;
#pragma unroll
    for (int l = 0; l < 20; ++l) {
      ax += enc[l] * W1f[l * 512 + t];
      ay += enc[l] * W1f[(20 + l) * 512 + t];
    }
    Tx[b * 512 + t] = ax;
    Ty[b * 512 + t] = ay;
  }
}

// ---------------------------------------------------------------------------
// Main fused kernel. Block = 512 thr (8 waves), BM=128 (16x8 pixel patch),
// BN=512, K=512 in 32 steps of 16 k. Whole A tile (128KB) resident in LDS.
// Wave w: ALL 128 pixels x n-cols [w*64, +64) (no B duplication).
// Per step per wave: 4 A ds_read_b128 + 2 B 16B loads (both prefetched one
// step ahead into areg/breg rotations), 8 MFMA 32x32x16.
// acc[mf][nn] reg r: h2[pix = mf*32 + (lane&31)]
//                   [n = w*64 + nn*32 + (r&3) + 8*(r>>2) + 4*(lane>>5)]
// ---------------------------------------------------------------------------
__global__ __launch_bounds__(512, 2) void main_kernel(
    const float* __restrict__ Tx, const float* __restrict__ Ty,
    const float* __restrict__ tvec,
    const unsigned short* __restrict__ W2s, const float* __restrict__ b2f,
    const float* __restrict__ W3f, const float* __restrict__ b3f,
    float* __restrict__ out) {
  __shared__ __attribute__((aligned(16))) unsigned short Ab[32 * 2048];  // 128KB: 32 steps x (128 pix x 16 k)
  __shared__ float part[8][128][3];                                      // 12KB

  const int t = threadIdx.x;
  const int w = t >> 6;            // wave id 0..7 (owns n-slice [w*64,+64))
  const int lane = t & 63;
  const int lo = lane & 31;
  const int hi = lane >> 5;
  const int x0 = blockIdx.x * 16, y0 = blockIdx.y * 8;

  // per-wave K-phase offset over the 32 steps (SGPR)
  const int kofs = __builtin_amdgcn_readfirstlane((w * 4) & 31);

  // B: frag (kstep, nn) at W2s + kstep*8192 + (w*2+nn)*512 + lane*8
  const unsigned short* bptr = W2s + (w * 2) * 512 + lane * 8;

  // ---- A fill (whole tile, once): thread (p = t>>2, s = t&3) covers pixel
  // p (0..127), k = 16*g + s*4..+3. Element (p,k) at (shorts)
  //   (k>>4)*2048 + (p>>5)*512 + ((k>>3)&1)*256 + (p&31)*8 + (k&7)
  // Frag read at lane l: step*2048 + mf*512 + l*8 (1KB contiguous, c-free).
  // Runs before acc/areg are live => deep load pipelining, no spill.
  {
    const int p = t >> 2, s = t & 3;
    const int xi = x0 + (p >> 3), yi = y0 + (p & 7);
    const float* txp = Tx + xi * 512 + s * 4;
    const float* typ = Ty + yi * 512 + s * 4;
    const float* tvp = tvec + s * 4;
    const int abase = (p >> 5) * 512 + (s >> 1) * 256 + (p & 31) * 8 + (s & 1) * 4;
#pragma unroll
    for (int g = 0; g < 32; ++g) {
      float4 a = *(const float4*)(txp + g * 16);
      float4 b = *(const float4*)(typ + g * 16);
      float4 tv = *(const float4*)(tvp + g * 16);
      float v0 = fmaxf(a.x + b.x + tv.x, 0.f);
      float v1 = fmaxf(a.y + b.y + tv.y, 0.f);
      float v2 = fmaxf(a.z + b.z + tv.z, 0.f);
      float v3 = fmaxf(a.w + b.w + tv.w, 0.f);
      uint2 pk;
      asm("v_cvt_pk_bf16_f32 %0, %1, %2" : "=v"(pk.x) : "v"(v0), "v"(v1));
      asm("v_cvt_pk_bf16_f32 %0, %1, %2" : "=v"(pk.y) : "v"(v2), "v"(v3));
      *(uint2*)&Ab[g * 2048 + abase] = pk;
    }
  }

  // ---- B pipeline init: depth 1 (2 buffers). breg[ks&1] used at pos ks. ----
  bf16x8 breg[2][2];
#pragma unroll
  for (int nn = 0; nn < 2; ++nn)
    breg[0][nn] = *(const bf16x8*)(bptr + kofs * 8192 + nn * 512);

  f32x16 acc[4][2];
#pragma unroll
  for (int mf = 0; mf < 4; ++mf)
#pragma unroll
    for (int nn = 0; nn < 2; ++nn)
#pragma unroll
      for (int r = 0; r < 16; ++r) acc[mf][nn][r] = 0.f;

  __syncthreads();  // publishes A; the only barrier before the epilogue

  // ---- A pipeline init: depth 1. areg[ks&1] used at pos ks. ----
  bf16x8 areg[2][4];
#pragma unroll
  for (int mf = 0; mf < 4; ++mf)
    areg[0][mf] = *(const bf16x8*)&Ab[kofs * 2048 + mf * 512 + lane * 8];

  // ---- K-loop: 32 steps, fully unrolled, no barriers, wave-staggered.
  // Loads for step ks+1 issued before this step's MFMAs => every load
  // rides a full 512-cyc MFMA step; no at-use waits. ----
#pragma unroll
  for (int ks = 0; ks < 32; ++ks) {
    const int kkl = (ks + kofs) & 31;
    if (ks < 31) {
      const int knl = (kkl + 1) & 31;
#pragma unroll
      for (int nn = 0; nn < 2; ++nn)
        breg[(ks + 1) & 1][nn] =
            *(const bf16x8*)(bptr + knl * 8192 + nn * 512);
      const unsigned short* arow = &Ab[knl * 2048 + lane * 8];
#pragma unroll
      for (int mf = 0; mf < 4; ++mf)
        areg[(ks + 1) & 1][mf] = *(const bf16x8*)&arow[mf * 512];
    }
    __builtin_amdgcn_s_setprio(1);
#pragma unroll
    for (int nn = 0; nn < 2; ++nn) {
      acc[0][nn] = __builtin_amdgcn_mfma_f32_32x32x16_bf16(
          breg[ks & 1][nn], areg[ks & 1][0], acc[0][nn], 0, 0, 0);
      acc[1][nn] = __builtin_amdgcn_mfma_f32_32x32x16_bf16(
          breg[ks & 1][nn], areg[ks & 1][1], acc[1][nn], 0, 0, 0);
      acc[2][nn] = __builtin_amdgcn_mfma_f32_32x32x16_bf16(
          breg[ks & 1][nn], areg[ks & 1][2], acc[2][nn], 0, 0, 0);
      acc[3][nn] = __builtin_amdgcn_mfma_f32_32x32x16_bf16(
          breg[ks & 1][nn], areg[ks & 1][3], acc[3][nn], 0, 0, 0);
    }
    __builtin_amdgcn_s_setprio(0);
  }

  // ---- epilogue: h2 = relu(acc + b2f); rgb partial = h2 @ W3f.
  // Lane: pixels mf*32+lo, n-cols w*64 + nn*32 + rq*8 + hi*4 + e.
  // W3/bias loads hoisted over mf. shfl_xor(32) combines hi-halves. ----
  {
    float p3[4][3];
#pragma unroll
    for (int mf = 0; mf < 4; ++mf) {
      p3[mf][0] = 0.f; p3[mf][1] = 0.f; p3[mf][2] = 0.f;
    }
#pragma unroll
    for (int nn = 0; nn < 2; ++nn) {
#pragma unroll
      for (int rq = 0; rq < 4; ++rq) {
        const int n0 = w * 64 + nn * 32 + rq * 8 + hi * 4;
        float4 bv = *(const float4*)&b2f[n0];
        float4 u0 = *(const float4*)&W3f[n0 * 3 + 0];
        float4 u1 = *(const float4*)&W3f[n0 * 3 + 4];
        float4 u2 = *(const float4*)&W3f[n0 * 3 + 8];
#pragma unroll
        for (int mf = 0; mf < 4; ++mf) {
          float h0 = fmaxf(acc[mf][nn][rq * 4 + 0] + bv.x, 0.f);
          float h1 = fmaxf(acc[mf][nn][rq * 4 + 1] + bv.y, 0.f);
          float h2 = fmaxf(acc[mf][nn][rq * 4 + 2] + bv.z, 0.f);
          float h3 = fmaxf(acc[mf][nn][rq * 4 + 3] + bv.w, 0.f);
          p3[mf][0] += h0 * u0.x + h1 * u0.w + h2 * u1.z + h3 * u2.y;
          p3[mf][1] += h0 * u0.y + h1 * u1.x + h2 * u1.w + h3 * u2.z;
          p3[mf][2] += h0 * u0.z + h1 * u1.y + h2 * u2.x + h3 * u2.w;
        }
      }
    }
#pragma unroll
    for (int mf = 0; mf < 4; ++mf)
#pragma unroll
      for (int cc = 0; cc < 3; ++cc)
        p3[mf][cc] += __shfl_xor(p3[mf][cc], 32, 64);
    if (hi == 0) {
#pragma unroll
      for (int mf = 0; mf < 4; ++mf)
#pragma unroll
        for (int cc = 0; cc < 3; ++cc)
          part[w][mf * 32 + lo][cc] = p3[mf][cc];
    }
  }
  __syncthreads();
  if (t < 384) {
    const int c = t >> 7, pp = t & 127;
    float sum = b3f[c];
#pragma unroll
    for (int ww = 0; ww < 8; ++ww) sum += part[ww][pp][c];
    out[c * NPIX + (x0 + (pp >> 3)) * 512 + (y0 + (pp & 7))] = sum;
  }
}

// ---------------------------------------------------------------------------
// Inputs: 0 coords (unused), 1 W1p, 2 b1p, 3 W2p, 4 b2p, 5 W1f, 6 b1f,
//         7 W2f, 8 b2f, 9 W3f, 10 b3f, 11 idx
// ---------------------------------------------------------------------------
extern "C" void kernel_launch(void* const* d_in, const int* in_sizes, int n_in,
                              void* d_out, int out_size, void* d_ws, size_t ws_size,
                              hipStream_t stream) {
  const float* W1p = (const float*)d_in[1];
  const float* b1p = (const float*)d_in[2];
  const float* W2p = (const float*)d_in[3];
  const float* b2p = (const float*)d_in[4];
  const float* W1f = (const float*)d_in[5];
  const float* b1f = (const float*)d_in[6];
  const float* W2f = (const float*)d_in[7];
  const float* b2f = (const float*)d_in[8];
  const float* W3f = (const float*)d_in[9];
  const float* b3f = (const float*)d_in[10];
  const int* idx = (const int*)d_in[11];
  float* out = (float*)d_out;

  char* ws = (char*)d_ws;
  float* Tx = (float*)ws;                                    // 1 MB
  float* Ty = (float*)(ws + (1u << 20));                     // 1 MB
  unsigned short* W2s = (unsigned short*)(ws + (2u << 20));  // 512 KB
  float* tvec = (float*)(ws + (2u << 20) + (512u << 10));    // 2 KB

  hipLaunchKernelGGL(pre_kernel, dim3(1025), dim3(512), 0, stream,
                     W1p, b1p, W2p, b2p, W1f, b1f, W2f, idx, Tx, Ty, W2s, tvec);
  hipLaunchKernelGGL(main_kernel, dim3(32, 64), dim3(512), 0, stream,
                     Tx, Ty, tvec, W2s, b2f, W3f, b3f, out);
}